// Round 10
// baseline (312.853 us; speedup 1.0000x reference)
//
#include <hip/hip_runtime.h>
#include <hip/hip_bf16.h>

// AttentivePredictionFusion: B=8, T=2048, D=512, H=128. fp32 in, fp32 out.
// R18: attn re-tiled q64->q32 (grid 512->1024) — adds occupancy WITHOUT
// duplicating QK work (R13's mistake was splitting d; splitting q only
// doubles K-staging L2 traffic, ~5 of 34 TB/s).
//  - Block: 32 q-rows x 256 d-cols, s-block 128 (16 iters). Wave w: QK
//    S[0:32][w*32..+32] (8 MFMA, Q hoisted in regs), PV O[0:32][w*64..+64]
//    (16 MFMA, V direct from blocked vT).
//  - LDS 40.9KB (sK 32K single-buf + sP 32x132 pad + sRS) -> 3 blocks/CU
//    = 12 waves/CU (was 8). VGPR est ~160 under the (256,3)=168 cap.
//  - sP: +4-u16 row pad (stride 132) instead of XOR swizzle -> 2-way banks
//    (sP is VALU-written so padding is legal; DMA'd sK keeps swizzle).
//  - Race fix vs R17: top-of-iter "vmcnt(0); s_barrier" so ALL waves' K-DMA
//    chunks landed before any wave reads sK. K-DMA issued after the sP
//    barrier (WAR-safe: lgkm(0)+barrier implies all QK reads done).
//  - gemm_body: f2bf_hw in bf16 epilogue. Rest identical to R17.

#define APF_B 8
#define APF_T 2048
#define APF_D 512
#define APF_H 128
#define APF_M (APF_B * APF_T)   // 16384

// gemm LDS slot swizzle (u16 units within a 32-u16 row)
#define GSWZ(row) ((((row) >> 1) & 3) << 3)
#define FA_LDP 132              // sP row stride (u16): 264B -> 2-way banks

typedef unsigned short u16;
typedef __attribute__((ext_vector_type(8))) short short8;
typedef __attribute__((ext_vector_type(4))) float f32x4;
typedef __attribute__((ext_vector_type(16))) float f32x16;

static __device__ __forceinline__ u16 f2bf(float x) {
    union { float f; unsigned int u; } cv;
    cv.f = x;
    unsigned int u = cv.u + 0x7FFFu + ((cv.u >> 16) & 1u);  // RNE
    return (u16)(u >> 16);
}
static __device__ __forceinline__ u16 f2bf_hw(float x) {
    union { __hip_bfloat16 h; u16 u; } cv;
    cv.h = __float2bfloat16(x);
    return cv.u;
}

// async global->LDS, 16 B per lane; LDS dest = wave-uniform base + lane*16
static __device__ __forceinline__ void load16_lds(const u16* g, u16* l) {
    __builtin_amdgcn_global_load_lds(
        (const __attribute__((address_space(1))) unsigned int*)g,
        (__attribute__((address_space(3))) unsigned int*)l,
        16, 0, 0);
}

// barrier that keeps the N newest VMEM ops in flight (T4 counted vmcnt)
template <int N>
static __device__ __forceinline__ void bar_keep() {
    if constexpr (N == 0)
        asm volatile("s_waitcnt vmcnt(0) lgkmcnt(0)\ns_barrier" ::: "memory");
    else if constexpr (N == 4)
        asm volatile("s_waitcnt vmcnt(4) lgkmcnt(0)\ns_barrier" ::: "memory");
    else if constexpr (N == 8)
        asm volatile("s_waitcnt vmcnt(8) lgkmcnt(0)\ns_barrier" ::: "memory");
}

static __device__ __forceinline__ f32x16 zero16() {
    f32x16 v;
#pragma unroll
    for (int i = 0; i < 16; ++i) v[i] = 0.f;
    return v;
}

// ---------------- prep kernel: LDS-tiled weight transposes ----------------
__global__ __launch_bounds__(256) void prep_w(
    const float* __restrict__ Wq, u16* __restrict__ WqT,
    const float* __restrict__ Wk, u16* __restrict__ WkT,
    const float* __restrict__ Wv, u16* __restrict__ WvT,
    const float* __restrict__ Wf, u16* __restrict__ WfT)
{
    __shared__ float tile[64][65];
    int b = blockIdx.x;
    const float* src; u16* dst; int K, N;
    if (b < 16)      { src = Wq; dst = WqT; K = 512;  N = 128; }
    else if (b < 32) { b -= 16; src = Wk; dst = WkT; K = 512;  N = 128; }
    else if (b < 96) { b -= 32; src = Wv; dst = WvT; K = 512;  N = 512; }
    else             { b -= 96; src = Wf; dst = WfT; K = 1024; N = 512; }
    const int ntN = N >> 6;
    const int k0 = (b / ntN) * 64, n0 = (b % ntN) * 64;

    const int tid = threadIdx.x;
#pragma unroll
    for (int rep = 0; rep < 4; ++rep) {
        const int r = (tid >> 4) + rep * 16;     // 0..63 (k)
        const int c = (tid & 15) * 4;            // 0..60 (n)
        const float4 v = *(const float4*)&src[(long)(k0 + r) * N + n0 + c];
        tile[r][c] = v.x; tile[r][c + 1] = v.y;
        tile[r][c + 2] = v.z; tile[r][c + 3] = v.w;
    }
    __syncthreads();
#pragma unroll
    for (int rep = 0; rep < 2; ++rep) {
        const int rn = (tid >> 3) + rep * 32;    // 0..63 (n)
        const int ck = (tid & 7) * 8;            // 0..56 (k)
        short8 o;
#pragma unroll
        for (int j = 0; j < 8; ++j)
            o[j] = (short)f2bf_hw(tile[ck + j][rn]);
        *(short8*)&dst[(long)(n0 + rn) * K + k0 + ck] = o;
    }
}

// ---------------- GEMM body (device function) ----------------
// C[128][128] tile = A[M][K] @ B[N][K]^T (+ bias / + Cadd).
// ADT: 0 = A bf16 (DMA, swizzled src), 1 = A fp32 (reg-stage + HW cvt).
// EPI: 0 bf16 store +bias; 2 fp32 sigmoid +bias; 3 fp32 raw +bias;
//      4 fp32 sigmoid(acc + Cadd[m][n]).
// BIASM: 0 bias[n]; 1 bias[m].   VBLK: 1 -> blocked [m/32][n/8][m&31][n&7].
// Pipeline per iter: issue regload(t+1) -> bar_keep<NREG> (drains only
// dma(t); regloads cross) -> issue dma(t+1) -> MFMA(t) -> ds_write(t+1).
template <int ADT, int BDT, int EPI, int BIASM, int VBLK>
static __device__ __forceinline__ void gemm_body(
    u16 (&smA)[2][4096], u16 (&smB)[2][4096],
    const void* Ap, long lda,
    const void* Bp, long ldb,
    const float* bias, void* Cp, long ldc, int K,
    long row0, long col0, const float* Cadd)
{
    const int tid  = threadIdx.x;
    const int lane = tid & 63;
    const int wid  = tid >> 6;
    const int wr   = wid >> 1;
    const int wc   = wid & 1;

    f32x4 acc[4][4];
#pragma unroll
    for (int i = 0; i < 4; ++i)
#pragma unroll
        for (int j = 0; j < 4; ++j)
            acc[i][j] = (f32x4){0.f, 0.f, 0.f, 0.f};

    const int lrow = (lane >> 4) * 4;
    const int lcol = lane & 15;
    const int q8   = (lane >> 4) * 8;

    float4 ra[2][2], rb[2][2];

    auto loadA = [&](int kb) {
        if (ADT == 1) {
            const float* Af = (const float*)Ap;
#pragma unroll
            for (int rep = 0; rep < 2; ++rep) {
                const int c = tid + rep * 256;
                const int rr = c >> 2, kc = (c & 3) * 8;
                const float* ga = Af + (row0 + rr) * lda + kb + kc;
                ra[rep][0] = *(const float4*)ga;
                ra[rep][1] = *(const float4*)(ga + 4);
            }
        }
    };
    auto loadB = [&](int kb) {
        if (BDT == 1) {
            const float* Bf = (const float*)Bp;
#pragma unroll
            for (int rep = 0; rep < 2; ++rep) {
                const int c = tid + rep * 256;
                const int rr = c >> 2, kc = (c & 3) * 8;
                const float* gb = Bf + (col0 + rr) * ldb + kb + kc;
                rb[rep][0] = *(const float4*)gb;
                rb[rep][1] = *(const float4*)(gb + 4);
            }
        }
    };
    auto dmaA = [&](int buf, int kb) {
        if (ADT == 0) {
            const u16* Ab = (const u16*)Ap;
#pragma unroll
            for (int rep = 0; rep < 2; ++rep) {
                const int c = tid + rep * 256;
                const int rr = c >> 2, kc = (c & 3) * 8;
                const int wbase = (wid * 64 + rep * 256) * 8;
                load16_lds(Ab + (row0 + rr) * lda + kb + (kc ^ GSWZ(rr)),
                           &smA[buf][wbase]);
            }
        }
    };
    auto dmaB = [&](int buf, int kb) {
        if (BDT == 0) {
            const u16* Bb = (const u16*)Bp;
#pragma unroll
            for (int rep = 0; rep < 2; ++rep) {
                const int c = tid + rep * 256;
                const int rr = c >> 2, kc = (c & 3) * 8;
                const int wbase = (wid * 64 + rep * 256) * 8;
                load16_lds(Bb + (col0 + rr) * ldb + kb + (kc ^ GSWZ(rr)),
                           &smB[buf][wbase]);
            }
        }
    };
    auto cvt8 = [&](const float4& a, const float4& b) {
        short8 v;
        v[0] = (short)f2bf_hw(a.x); v[1] = (short)f2bf_hw(a.y);
        v[2] = (short)f2bf_hw(a.z); v[3] = (short)f2bf_hw(a.w);
        v[4] = (short)f2bf_hw(b.x); v[5] = (short)f2bf_hw(b.y);
        v[6] = (short)f2bf_hw(b.z); v[7] = (short)f2bf_hw(b.w);
        return v;
    };
    auto writeA = [&](int buf) {
        if (ADT == 1) {
#pragma unroll
            for (int rep = 0; rep < 2; ++rep) {
                const int c = tid + rep * 256;
                *(short8*)&smA[buf][(c * 8) ^ GSWZ(c >> 2)] =
                    cvt8(ra[rep][0], ra[rep][1]);
            }
        }
    };
    auto writeB = [&](int buf) {
        if (BDT == 1) {
#pragma unroll
            for (int rep = 0; rep < 2; ++rep) {
                const int c = tid + rep * 256;
                *(short8*)&smB[buf][(c * 8) ^ GSWZ(c >> 2)] =
                    cvt8(rb[rep][0], rb[rep][1]);
            }
        }
    };

    // per-wave VMEM instrs that stay in flight across the barrier
    constexpr int NREG = (ADT == 1 ? 4 : 0) + (BDT == 1 ? 4 : 0);

    const int NT = K / 32;
    loadA(0); loadB(0);
    writeA(0); writeB(0);
    dmaA(0, 0); dmaB(0, 0);

    int cur = 0;
    for (int t = 0; t < NT; ++t) {
        const int kb2 = (t + 1) * 32;
        if (t + 1 < NT) {
            loadA(kb2); loadB(kb2);     // fp32 reg loads: cross the barrier
            bar_keep<NREG>();           // drains dma(t) + prev ds_writes only
            dmaA(cur ^ 1, kb2); dmaB(cur ^ 1, kb2);  // post-bar: WAR-safe
        } else {
            bar_keep<0>();
        }

        short8 av[4], bv4[4];
#pragma unroll
        for (int ti = 0; ti < 4; ++ti) {
            const int arow = wr * 64 + ti * 16 + lcol;
            av[ti] = *(const short8*)&smA[cur][arow * 32 + (q8 ^ GSWZ(arow))];
        }
#pragma unroll
        for (int tj = 0; tj < 4; ++tj) {
            const int brow = wc * 64 + tj * 16 + lcol;
            bv4[tj] = *(const short8*)&smB[cur][brow * 32 + (q8 ^ GSWZ(brow))];
        }

#pragma unroll
        for (int ti = 0; ti < 4; ++ti)
#pragma unroll
            for (int tj = 0; tj < 4; ++tj)
                acc[ti][tj] = __builtin_amdgcn_mfma_f32_16x16x32_bf16(
                    av[ti], bv4[tj], acc[ti][tj], 0, 0, 0);

        if (t + 1 < NT) { writeA(cur ^ 1); writeB(cur ^ 1); }
        cur ^= 1;
    }

#pragma unroll
    for (int ti = 0; ti < 4; ++ti) {
        const long m0t = row0 + wr * 64 + ti * 16 + lrow;
#pragma unroll
        for (int tj = 0; tj < 4; ++tj) {
            const long n = col0 + wc * 64 + tj * 16 + lcol;
            const float bn = (BIASM == 0 && bias != nullptr) ? bias[n] : 0.f;
            if (EPI == 0) {
                u16* C = (u16*)Cp;
#pragma unroll
                for (int r = 0; r < 4; ++r) {
                    const long m = m0t + r;
                    const float bm = (BIASM == 1) ? bias[m] : bn;
                    long idx;
                    if (VBLK) {
                        idx = ((((m >> 5) * 256) + (n >> 3)) << 8) +
                              ((m & 31) << 3) + (n & 7);
                    } else {
                        idx = m * ldc + n;
                    }
                    C[idx] = f2bf_hw(acc[ti][tj][r] + bm);
                }
            } else if (EPI == 2) {
                float* C = (float*)Cp;
#pragma unroll
                for (int r = 0; r < 4; ++r) {
                    const float val = acc[ti][tj][r] + bn;
                    C[(m0t + r) * ldc + n] = 1.0f / (1.0f + expf(-val));
                }
            } else if (EPI == 3) {
                float* C = (float*)Cp;
#pragma unroll
                for (int r = 0; r < 4; ++r)
                    C[(m0t + r) * ldc + n] = acc[ti][tj][r] + bn;
            } else {  // EPI == 4
                float* C = (float*)Cp;
#pragma unroll
                for (int r = 0; r < 4; ++r) {
                    const float val = acc[ti][tj][r] + Cadd[(m0t + r) * ldc + n];
                    C[(m0t + r) * ldc + n] = 1.0f / (1.0f + expf(-val));
                }
            }
        }
    }
}

// ---------------- mid GEMMs: q/k proj + vT + Cpre, one 1280-block launch ---
__global__ __launch_bounds__(256, 3) void mid_gemms(
    const float* __restrict__ x, const float* __restrict__ pred,
    const u16* __restrict__ WqT, const u16* __restrict__ WkT,
    const u16* __restrict__ WvT, const u16* __restrict__ WfT,
    const float* __restrict__ bq, const float* __restrict__ bk,
    const float* __restrict__ bv, const float* __restrict__ bfu,
    u16* __restrict__ qb, u16* __restrict__ kbuf, u16* __restrict__ vTb,
    float* __restrict__ Cpre)
{
    __shared__ u16 smA[2][4096];
    __shared__ u16 smB[2][4096];

    const int bid = blockIdx.x;
    if (bid < 256) {
        const int zz = bid >> 7, by = bid & 127;
        gemm_body<1, 0, 0, 0, 0>(smA, smB,
            zz ? (const void*)x : (const void*)pred, APF_D,
            zz ? WkT : WqT, APF_D,
            zz ? bk : bq, zz ? (void*)kbuf : (void*)qb, APF_H, APF_D,
            (long)by * 128, 0, nullptr);
    } else if (bid < 768) {
        const int t = bid - 256;
        const int zz = t >> 6, rem = t & 63;
        const int bx = rem & 15, by = rem >> 4;
        gemm_body<0, 1, 0, 1, 1>(smA, smB,
            WvT, APF_D,
            (const void*)(x + (long)zz * APF_T * APF_D), APF_D,
            bv, (void*)(vTb + (long)zz * 1048576L), APF_T, APF_D,
            (long)by * 128, (long)bx * 128, nullptr);
    } else {
        const int t = bid - 768;          // 512 blocks: 128 m-tiles x 4 n-tiles
        const int bx = t & 3, by = t >> 2;
        gemm_body<1, 0, 3, 0, 0>(smA, smB,
            (const void*)pred, APF_D,
            WfT, 1024,
            bfu, (void*)Cpre, APF_D, APF_D,
            (long)by * 128, (long)bx * 128, nullptr);
    }
}

// ---------------- fusion GEMM: out = sigmoid(att@Wf_bot + Cpre) ----------
__global__ __launch_bounds__(256, 2) void fusion_gemm(
    const u16* __restrict__ attb, const u16* __restrict__ WfT,
    const float* __restrict__ Cpre, float* __restrict__ out)
{
    __shared__ u16 smA[2][4096];
    __shared__ u16 smB[2][4096];
    gemm_body<0, 0, 4, 0, 0>(smA, smB,
        (const void*)attb, APF_D,
        WfT + 512, 1024,
        nullptr, (void*)out, APF_D, APF_D,
        (long)blockIdx.y * 128, (long)blockIdx.x * 128, Cpre);
}

// ---------------- fused attention (R18: q32 tiles, 3 blocks/CU) ----------
// Grid 1024: bid&7 = z (XCD L2); (bid>>3)&63 = q-tile (32 rows); bid>>9 =
// d-chunk (256 cols). 4 waves, s-block 128, 16 iters.
// Per iter: [vmcnt(0)+bar: all waves' K-DMA landed] QK (wave w: S[0:32]
// [w*32..+32], 8 MFMA, Q from regs) -> V1 loads -> exp+sP -> [lgkm(0)+bar:
// sP published, QK reads all done] -> K-DMA(kt+1) issue -> PV-b1 -> V2 ->
// PV-b2 (wave w: O[0:32][w*64..+64], 16 MFMA total).
// LDS 40.9KB -> 3 blocks/CU (12 waves). VGPR est ~160 < 168 cap.
__global__ __launch_bounds__(256, 3) void attn_fused(
    const u16* __restrict__ qg, const u16* __restrict__ kg,
    const u16* __restrict__ vTg, u16* __restrict__ attg)
{
    __shared__ u16 sK[128 * 128];    // 32 KB, single buffer
    __shared__ u16 sP[32 * FA_LDP];  // 8.25 KB (pad stride 132)
    __shared__ float sRS[160];       // partials [4][32] + inv [32]

    const int tid  = threadIdx.x;
    const int lane = tid & 63;
    const int w    = tid >> 6;       // 0..3
    const int l31  = lane & 31;
    const int hi   = lane >> 5;      // 0..1

    const int  bid = blockIdx.x;
    const long z   = bid & 7;
    const long q0  = (long)((bid >> 3) & 63) * 32;
    const long d0  = (long)(bid >> 9) * 256;

    const u16* kbase0 = kg + z * (long)APF_T * APF_H;

    // prologue: K tile 0 DMA (pre-swizzled source, linear LDS), 128x128
#pragma unroll
    for (int rep = 0; rep < 8; ++rep) {
        const int c    = tid + rep * 256;     // 0..2047
        const int row  = c >> 4;
        const int col8 = (c & 15) * 8;
        load16_lds(kbase0 + row * APF_H + (col8 ^ ((row & 15) << 3)),
                   &sK[c * 8]);
    }

    // Q hoist: all waves share the same 32 q-rows (lane row = q0 + l31)
    short8 qf[8];
    {
        const u16* qsrc = qg + (z * APF_T + q0 + l31) * APF_H;
#pragma unroll
        for (int ks = 0; ks < 8; ++ks)
            qf[ks] = *(const short8*)(qsrc + ks * 16 + hi * 8);
    }

    f32x16 oacc[2];
    oacc[0] = zero16(); oacc[1] = zero16();
    f32x16 rsacc = zero16();

    // blocked vT base: wave w owns d-blocks dblk0, dblk0+1 (64 d-cols)
    const long dblk0 = (d0 >> 5) + w * 2;
    const u16* vzb = vTg + z * 1048576L + dblk0 * 65536L + (long)l31 * 8;

    const int krow = w * 32 + l31;   // sK B-operand rows for wave w
    const int pcol = w * 32 + l31;   // sP columns owned by wave w

    for (int kt = 0; kt < APF_T / 128; ++kt) {
        // all waves' K-DMA chunks landed (own vmcnt) + cross-wave sync
        asm volatile("s_waitcnt vmcnt(0)\ns_barrier" ::: "memory");

        // QK^T: S[0:32][w*32..+32] over h=128 -> 8 k-steps
        f32x16 sacc = zero16();
#pragma unroll
        for (int ks = 0; ks < 8; ++ks) {
            const int colk = ks * 16 + hi * 8;
            const short8 bv =
                *(const short8*)&sK[krow * 128 + (colk ^ ((krow & 15) << 3))];
            sacc = __builtin_amdgcn_mfma_f32_32x32x16_bf16(qf[ks], bv, sacc, 0, 0, 0);
        }

        // V batch 1 (blocked layout: contiguous 1KB per instr), ks 0..3
        const long sbase = (long)kt * 16 + hi;
        short8 vf1[2][4];
#pragma unroll
        for (int dt = 0; dt < 2; ++dt)
#pragma unroll
            for (int ks = 0; ks < 4; ++ks)
                vf1[dt][ks] = *(const short8*)(vzb + dt * 65536L + (sbase + ks * 2) * 256);

        // exp + rowsum + P -> sP (padded stride; C-layout -> A-layout hop)
#pragma unroll
        for (int rg = 0; rg < 16; ++rg) {
            const float e = __expf(sacc[rg]);
            rsacc[rg] += e;
            const int prow = (rg & 3) + 8 * (rg >> 2) + 4 * hi;   // 0..31
            sP[prow * FA_LDP + pcol] = f2bf_hw(e);
        }
        // publish sP; all QK sK-reads done (lgkm drained + barrier)
        asm volatile("s_waitcnt lgkmcnt(0)\ns_barrier" ::: "memory");

        // K-DMA(kt+1): WAR-safe (all readers passed the barrier above);
        // lands by next iter's vmcnt(0)+barrier.
        if (kt + 1 < APF_T / 128) {
            const u16* ksrc = kbase0 + (long)(kt + 1) * 128 * APF_H;
#pragma unroll
            for (int rep = 0; rep < 8; ++rep) {
                const int c    = tid + rep * 256;
                const int row  = c >> 4;
                const int col8 = (c & 15) * 8;
                load16_lds(ksrc + row * APF_H + (col8 ^ ((row & 15) << 3)),
                           &sK[c * 8]);
            }
        }

        // PV batch 1 (ks 0..3): O[0:32][w*64..+64] += P @ V^T
#pragma unroll
        for (int ks = 0; ks < 4; ++ks) {
            const int colk = ks * 16 + hi * 8;
            const short8 pa = *(const short8*)&sP[l31 * FA_LDP + colk];
#pragma unroll
            for (int dt = 0; dt < 2; ++dt)
                oacc[dt] = __builtin_amdgcn_mfma_f32_32x32x16_bf16(
                    pa, vf1[dt][ks], oacc[dt], 0, 0, 0);
        }

        // V batch 2 + PV batch 2 (ks 4..7)
        short8 vf2[2][4];
#pragma unroll
        for (int dt = 0; dt < 2; ++dt)
#pragma unroll
            for (int ks = 0; ks < 4; ++ks)
                vf2[dt][ks] = *(const short8*)(vzb + dt * 65536L + (sbase + 8 + ks * 2) * 256);
#pragma unroll
        for (int ks = 0; ks < 4; ++ks) {
            const int colk = (ks + 4) * 16 + hi * 8;
            const short8 pa = *(const short8*)&sP[l31 * FA_LDP + colk];
#pragma unroll
            for (int dt = 0; dt < 2; ++dt)
                oacc[dt] = __builtin_amdgcn_mfma_f32_32x32x16_bf16(
                    pa, vf2[dt][ks], oacc[dt], 0, 0, 0);
        }
    }

    // rowsum: reduce over the 32 s-cols (l31 lanes), per-wave partials
#pragma unroll
    for (int rg = 0; rg < 16; ++rg) {
        float s = rsacc[rg];
        s += __shfl_xor(s, 1);
        s += __shfl_xor(s, 2);
        s += __shfl_xor(s, 4);
        s += __shfl_xor(s, 8);
        s += __shfl_xor(s, 16);
        rsacc[rg] = s;
    }
    if (l31 == 0) {
#pragma unroll
        for (int rg = 0; rg < 16; ++rg) {
            const int row = (rg & 3) + 8 * (rg >> 2) + 4 * hi;   // 0..31
            sRS[w * 32 + row] = rsacc[rg];
        }
    }
    __syncthreads();
    if (tid < 32) {
        sRS[128 + tid] = 1.0f / (sRS[tid] + sRS[32 + tid] +
                                 sRS[64 + tid] + sRS[96 + tid]);
    }
    __syncthreads();

    // store: 32 q rows x own 64 d cols
    const long rowg0 = z * APF_T + q0;
    const long colg0 = d0 + (long)w * 64;
#pragma unroll
    for (int rg = 0; rg < 16; ++rg) {
        const int row = (rg & 3) + 8 * (rg >> 2) + 4 * hi;
        const float inv = sRS[128 + row];
#pragma unroll
        for (int dt = 0; dt < 2; ++dt)
            attg[(rowg0 + row) * APF_D + colg0 + dt * 32 + l31] =
                f2bf_hw(oacc[dt][rg] * inv);
    }
}

extern "C" void kernel_launch(void* const* d_in, const int* in_sizes, int n_in,
                              void* d_out, int out_size, void* d_ws, size_t ws_size,
                              hipStream_t stream)
{
    (void)in_sizes; (void)n_in; (void)out_size; (void)ws_size;

    const float* x    = (const float*)d_in[0];
    const float* pred = (const float*)d_in[1];
    const float* Wq   = (const float*)d_in[2];
    const float* bq   = (const float*)d_in[3];
    const float* Wk   = (const float*)d_in[4];
    const float* bk   = (const float*)d_in[5];
    const float* Wv   = (const float*)d_in[6];
    const float* bv   = (const float*)d_in[7];
    const float* Wf   = (const float*)d_in[8];
    const float* bfu  = (const float*)d_in[9];

    // Workspace: Cpre fp32 32MB first, then u16 arrays (~42MB)
    float* Cpre = (float*)d_ws;                        // [16384][512] fp32
    u16* wsp  = (u16*)(Cpre + (long)APF_M * APF_D);
    u16* qb   = wsp;                                   // [16384][128]
    u16* kbuf = qb   + (long)APF_M * APF_H;            // [16384][128]
    u16* vTb  = kbuf + (long)APF_M * APF_H;            // [8][16][256][32][8] blocked
    u16* attb = vTb  + (long)APF_M * APF_D;            // [16384][512]
    u16* WqT  = attb + (long)APF_M * APF_D;            // [128][512]
    u16* WkT  = WqT  + (long)APF_H * APF_D;            // [128][512]
    u16* WvT  = WkT  + (long)APF_H * APF_D;            // [512][512]
    u16* WfT  = WvT  + (long)APF_D * APF_D;            // [512][1024]

    const dim3 thr(256);

    // weights -> bf16 transposed (LDS-tiled, coalesced)
    prep_w<<<dim3(224), thr, 0, stream>>>(Wq, WqT, Wk, WkT, Wv, WvT, Wf, WfT);

    // q,k projections + vT + Cpre(pred@Wf_top+bf) in one 1280-block launch
    mid_gemms<<<dim3(1280), thr, 0, stream>>>(
        x, pred, WqT, WkT, WvT, WfT, bq, bk, bv, bfu, qb, kbuf, vTb, Cpre);

    // fused attention: att = softmax(q k^T) v
    attn_fused<<<dim3(1024), thr, 0, stream>>>(qb, kbuf, vTb, attb);

    // out = sigmoid(att @ Wf_bot + Cpre)
    fusion_gemm<<<dim3(4, 128), thr, 0, stream>>>(attb, WfT, Cpre,
                                                  (float*)d_out);
}

// Round 11
// 276.114 us; speedup vs baseline: 1.1331x; 1.1331x over previous
//
#include <hip/hip_runtime.h>
#include <hip/hip_bf16.h>

// AttentivePredictionFusion: B=8, T=2048, D=512, H=128. fp32 in, fp32 out.
// R19: ALGEBRAIC fusion-elimination. Softmax norm is a per-row scalar =>
//   att@Wf_bot = diag(1/rs)(P@V)@Wf_bot = diag(1/rs)(P@(x@(Wv@Wf_bot)))
// and rows of P/rs sum to 1 => V-bias folds: bvf = bv@Wf_bot.
//   - wvf_gemm (16 blocks): WvfT = (Wv@Wf_bot)^T bf16.
//   - mid vT path produces V'^T = (x@Wvf + bvf)^T (same cost as old vT).
//   - attn epilogue: out = sigmoid(Cpre + oacc*inv) fp32, written directly.
//   - fusion_gemm DELETED (8.6 GF + attb 16MB write/read + 1 launch).
//   - prep_w drops the WvT transpose (64 blocks), adds bvf (2 blocks).
//   - attn body = R18-reverted to R16 (75.7us best, race-free 1-barrier
//     dbuf; R18's q32 split halved compute/block at constant staging ->
//     133us. Tiling is locally optimal at q64 x d256).
//   - GEMM side keeps R17 counted-vmcnt pipeline.

#define APF_B 8
#define APF_T 2048
#define APF_D 512
#define APF_H 128
#define APF_M (APF_B * APF_T)   // 16384

// gemm LDS slot swizzle (u16 units within a 32-u16 row)
#define GSWZ(row) ((((row) >> 1) & 3) << 3)

typedef unsigned short u16;
typedef __attribute__((ext_vector_type(8))) short short8;
typedef __attribute__((ext_vector_type(4))) float f32x4;
typedef __attribute__((ext_vector_type(16))) float f32x16;

static __device__ __forceinline__ u16 f2bf(float x) {
    union { float f; unsigned int u; } cv;
    cv.f = x;
    unsigned int u = cv.u + 0x7FFFu + ((cv.u >> 16) & 1u);  // RNE
    return (u16)(u >> 16);
}
static __device__ __forceinline__ u16 f2bf_hw(float x) {
    union { __hip_bfloat16 h; u16 u; } cv;
    cv.h = __float2bfloat16(x);
    return cv.u;
}

// async global->LDS, 16 B per lane; LDS dest = wave-uniform base + lane*16
static __device__ __forceinline__ void load16_lds(const u16* g, u16* l) {
    __builtin_amdgcn_global_load_lds(
        (const __attribute__((address_space(1))) unsigned int*)g,
        (__attribute__((address_space(3))) unsigned int*)l,
        16, 0, 0);
}

// barrier that keeps the N newest VMEM ops in flight (T4 counted vmcnt)
template <int N>
static __device__ __forceinline__ void bar_keep() {
    if constexpr (N == 0)
        asm volatile("s_waitcnt vmcnt(0) lgkmcnt(0)\ns_barrier" ::: "memory");
    else if constexpr (N == 4)
        asm volatile("s_waitcnt vmcnt(4) lgkmcnt(0)\ns_barrier" ::: "memory");
    else if constexpr (N == 8)
        asm volatile("s_waitcnt vmcnt(8) lgkmcnt(0)\ns_barrier" ::: "memory");
}

static __device__ __forceinline__ f32x16 zero16() {
    f32x16 v;
#pragma unroll
    for (int i = 0; i < 16; ++i) v[i] = 0.f;
    return v;
}

// ---------------- prep kernel: weight transposes + bvf ----------------
// b<16: Wq (512x128); b<32: Wk; b<160: Wf (1024x512, 128 tiles);
// b=160,161: bvf[e] = sum_c bv[c]*Wf[512+c][e] (fp32).
__global__ __launch_bounds__(256) void prep_w(
    const float* __restrict__ Wq, u16* __restrict__ WqT,
    const float* __restrict__ Wk, u16* __restrict__ WkT,
    const float* __restrict__ Wf, u16* __restrict__ WfT,
    const float* __restrict__ bv, float* __restrict__ bvf)
{
    __shared__ float tile[64][65];
    int b = blockIdx.x;
    const int tid = threadIdx.x;

    if (b >= 160) {  // bvf
        const int e = (b - 160) * 256 + tid;
        float acc = 0.f;
        for (int c = 0; c < 512; ++c)
            acc += bv[c] * Wf[(long)(512 + c) * 512 + e];
        bvf[e] = acc;
        return;
    }

    const float* src; u16* dst; int K, N;
    if (b < 16)      { src = Wq; dst = WqT; K = 512;  N = 128; }
    else if (b < 32) { b -= 16; src = Wk; dst = WkT; K = 512;  N = 128; }
    else             { b -= 32; src = Wf; dst = WfT; K = 1024; N = 512; }
    const int ntN = N >> 6;
    const int k0 = (b / ntN) * 64, n0 = (b % ntN) * 64;

#pragma unroll
    for (int rep = 0; rep < 4; ++rep) {
        const int r = (tid >> 4) + rep * 16;     // 0..63 (k)
        const int c = (tid & 15) * 4;            // 0..60 (n)
        const float4 v = *(const float4*)&src[(long)(k0 + r) * N + n0 + c];
        tile[r][c] = v.x; tile[r][c + 1] = v.y;
        tile[r][c + 2] = v.z; tile[r][c + 3] = v.w;
    }
    __syncthreads();
#pragma unroll
    for (int rep = 0; rep < 2; ++rep) {
        const int rn = (tid >> 3) + rep * 32;    // 0..63 (n)
        const int ck = (tid & 7) * 8;            // 0..56 (k)
        short8 o;
#pragma unroll
        for (int j = 0; j < 8; ++j)
            o[j] = (short)f2bf_hw(tile[ck + j][rn]);
        *(short8*)&dst[(long)(n0 + rn) * K + k0 + ck] = o;
    }
}

// ---------------- GEMM body (device function) ----------------
// C[128][128] tile = A[M][K] @ B[N][K]^T (+ bias / + Cadd).
// ADT: 0 = A bf16 (DMA, swizzled src), 1 = A fp32 (reg-stage + HW cvt).
// EPI: 0 bf16 store +bias; 3 fp32 raw +bias.
// BIASM: 0 bias[n]; 1 bias[m].   VBLK: 1 -> blocked [m/32][n/8][m&31][n&7].
// Pipeline per iter: issue regload(t+1) -> bar_keep<NREG> (drains only
// dma(t); regloads cross) -> issue dma(t+1) -> MFMA(t) -> ds_write(t+1).
template <int ADT, int BDT, int EPI, int BIASM, int VBLK>
static __device__ __forceinline__ void gemm_body(
    u16 (&smA)[2][4096], u16 (&smB)[2][4096],
    const void* Ap, long lda,
    const void* Bp, long ldb,
    const float* bias, void* Cp, long ldc, int K,
    long row0, long col0)
{
    const int tid  = threadIdx.x;
    const int lane = tid & 63;
    const int wid  = tid >> 6;
    const int wr   = wid >> 1;
    const int wc   = wid & 1;

    f32x4 acc[4][4];
#pragma unroll
    for (int i = 0; i < 4; ++i)
#pragma unroll
        for (int j = 0; j < 4; ++j)
            acc[i][j] = (f32x4){0.f, 0.f, 0.f, 0.f};

    const int lrow = (lane >> 4) * 4;
    const int lcol = lane & 15;
    const int q8   = (lane >> 4) * 8;

    float4 ra[2][2], rb[2][2];

    auto loadA = [&](int kb) {
        if (ADT == 1) {
            const float* Af = (const float*)Ap;
#pragma unroll
            for (int rep = 0; rep < 2; ++rep) {
                const int c = tid + rep * 256;
                const int rr = c >> 2, kc = (c & 3) * 8;
                const float* ga = Af + (row0 + rr) * lda + kb + kc;
                ra[rep][0] = *(const float4*)ga;
                ra[rep][1] = *(const float4*)(ga + 4);
            }
        }
    };
    auto loadB = [&](int kb) {
        if (BDT == 1) {
            const float* Bf = (const float*)Bp;
#pragma unroll
            for (int rep = 0; rep < 2; ++rep) {
                const int c = tid + rep * 256;
                const int rr = c >> 2, kc = (c & 3) * 8;
                const float* gb = Bf + (col0 + rr) * ldb + kb + kc;
                rb[rep][0] = *(const float4*)gb;
                rb[rep][1] = *(const float4*)(gb + 4);
            }
        }
    };
    auto dmaA = [&](int buf, int kb) {
        if (ADT == 0) {
            const u16* Ab = (const u16*)Ap;
#pragma unroll
            for (int rep = 0; rep < 2; ++rep) {
                const int c = tid + rep * 256;
                const int rr = c >> 2, kc = (c & 3) * 8;
                const int wbase = (wid * 64 + rep * 256) * 8;
                load16_lds(Ab + (row0 + rr) * lda + kb + (kc ^ GSWZ(rr)),
                           &smA[buf][wbase]);
            }
        }
    };
    auto dmaB = [&](int buf, int kb) {
        if (BDT == 0) {
            const u16* Bb = (const u16*)Bp;
#pragma unroll
            for (int rep = 0; rep < 2; ++rep) {
                const int c = tid + rep * 256;
                const int rr = c >> 2, kc = (c & 3) * 8;
                const int wbase = (wid * 64 + rep * 256) * 8;
                load16_lds(Bb + (col0 + rr) * ldb + kb + (kc ^ GSWZ(rr)),
                           &smB[buf][wbase]);
            }
        }
    };
    auto cvt8 = [&](const float4& a, const float4& b) {
        short8 v;
        v[0] = (short)f2bf_hw(a.x); v[1] = (short)f2bf_hw(a.y);
        v[2] = (short)f2bf_hw(a.z); v[3] = (short)f2bf_hw(a.w);
        v[4] = (short)f2bf_hw(b.x); v[5] = (short)f2bf_hw(b.y);
        v[6] = (short)f2bf_hw(b.z); v[7] = (short)f2bf_hw(b.w);
        return v;
    };
    auto writeA = [&](int buf) {
        if (ADT == 1) {
#pragma unroll
            for (int rep = 0; rep < 2; ++rep) {
                const int c = tid + rep * 256;
                *(short8*)&smA[buf][(c * 8) ^ GSWZ(c >> 2)] =
                    cvt8(ra[rep][0], ra[rep][1]);
            }
        }
    };
    auto writeB = [&](int buf) {
        if (BDT == 1) {
#pragma unroll
            for (int rep = 0; rep < 2; ++rep) {
                const int c = tid + rep * 256;
                *(short8*)&smB[buf][(c * 8) ^ GSWZ(c >> 2)] =
                    cvt8(rb[rep][0], rb[rep][1]);
            }
        }
    };

    // per-wave VMEM instrs that stay in flight across the barrier
    constexpr int NREG = (ADT == 1 ? 4 : 0) + (BDT == 1 ? 4 : 0);

    const int NT = K / 32;
    loadA(0); loadB(0);
    writeA(0); writeB(0);
    dmaA(0, 0); dmaB(0, 0);

    int cur = 0;
    for (int t = 0; t < NT; ++t) {
        const int kb2 = (t + 1) * 32;
        if (t + 1 < NT) {
            loadA(kb2); loadB(kb2);     // fp32 reg loads: cross the barrier
            bar_keep<NREG>();           // drains dma(t) + prev ds_writes only
            dmaA(cur ^ 1, kb2); dmaB(cur ^ 1, kb2);  // post-bar: WAR-safe
        } else {
            bar_keep<0>();
        }

        short8 av[4], bv4[4];
#pragma unroll
        for (int ti = 0; ti < 4; ++ti) {
            const int arow = wr * 64 + ti * 16 + lcol;
            av[ti] = *(const short8*)&smA[cur][arow * 32 + (q8 ^ GSWZ(arow))];
        }
#pragma unroll
        for (int tj = 0; tj < 4; ++tj) {
            const int brow = wc * 64 + tj * 16 + lcol;
            bv4[tj] = *(const short8*)&smB[cur][brow * 32 + (q8 ^ GSWZ(brow))];
        }

#pragma unroll
        for (int ti = 0; ti < 4; ++ti)
#pragma unroll
            for (int tj = 0; tj < 4; ++tj)
                acc[ti][tj] = __builtin_amdgcn_mfma_f32_16x16x32_bf16(
                    av[ti], bv4[tj], acc[ti][tj], 0, 0, 0);

        if (t + 1 < NT) { writeA(cur ^ 1); writeB(cur ^ 1); }
        cur ^= 1;
    }

#pragma unroll
    for (int ti = 0; ti < 4; ++ti) {
        const long m0t = row0 + wr * 64 + ti * 16 + lrow;
#pragma unroll
        for (int tj = 0; tj < 4; ++tj) {
            const long n = col0 + wc * 64 + tj * 16 + lcol;
            const float bn = (BIASM == 0 && bias != nullptr) ? bias[n] : 0.f;
            if (EPI == 0) {
                u16* C = (u16*)Cp;
#pragma unroll
                for (int r = 0; r < 4; ++r) {
                    const long m = m0t + r;
                    const float bm = (BIASM == 1) ? bias[m] : bn;
                    long idx;
                    if (VBLK) {
                        idx = ((((m >> 5) * 256) + (n >> 3)) << 8) +
                              ((m & 31) << 3) + (n & 7);
                    } else {
                        idx = m * ldc + n;
                    }
                    C[idx] = f2bf_hw(acc[ti][tj][r] + bm);
                }
            } else {  // EPI == 3
                float* C = (float*)Cp;
#pragma unroll
                for (int r = 0; r < 4; ++r)
                    C[(m0t + r) * ldc + n] = acc[ti][tj][r] + bn;
            }
        }
    }
}

// ---------------- wvf GEMM: WvfT = (Wv @ Wf_bot)^T, bf16 [512][512] -------
// WvfT[e][d] = sum_c Wf[512+c][e] * Wv[d][c]
//   A[e][c] = WfT[e][512+c] (bf16, lda=1024, ptr WfT+512)
//   B[d][c] = Wv[d][c]      (fp32, ldb=512)
__global__ __launch_bounds__(256, 2) void wvf_gemm(
    const u16* __restrict__ WfT, const float* __restrict__ Wv,
    u16* __restrict__ WvfT)
{
    __shared__ u16 smA[2][4096];
    __shared__ u16 smB[2][4096];
    gemm_body<0, 1, 0, 0, 0>(smA, smB,
        (const void*)(WfT + 512), 1024,
        (const void*)Wv, APF_D,
        nullptr, (void*)WvfT, APF_D, APF_D,
        (long)blockIdx.y * 128, (long)blockIdx.x * 128);
}

// ---------------- mid GEMMs: q/k proj + v'T + Cpre, 1280-block launch -----
// bid<256: qk. zz=bid>>7 (0:q pred/WqT, 1:k x/WkT), by=bid&127.
// 256..767: v'T = (x@Wvf + bvf)^T blocked. A=WvfT bf16, B=x fp32, bias bvf.
// 768..1279: Cpre = pred @ WfT_top^T + bf (fp32 raw).
__global__ __launch_bounds__(256, 3) void mid_gemms(
    const float* __restrict__ x, const float* __restrict__ pred,
    const u16* __restrict__ WqT, const u16* __restrict__ WkT,
    const u16* __restrict__ WvfT, const u16* __restrict__ WfT,
    const float* __restrict__ bq, const float* __restrict__ bk,
    const float* __restrict__ bvf, const float* __restrict__ bfu,
    u16* __restrict__ qb, u16* __restrict__ kbuf, u16* __restrict__ vTb,
    float* __restrict__ Cpre)
{
    __shared__ u16 smA[2][4096];
    __shared__ u16 smB[2][4096];

    const int bid = blockIdx.x;
    if (bid < 256) {
        const int zz = bid >> 7, by = bid & 127;
        gemm_body<1, 0, 0, 0, 0>(smA, smB,
            zz ? (const void*)x : (const void*)pred, APF_D,
            zz ? WkT : WqT, APF_D,
            zz ? bk : bq, zz ? (void*)kbuf : (void*)qb, APF_H, APF_D,
            (long)by * 128, 0);
    } else if (bid < 768) {
        const int t = bid - 256;
        const int zz = t >> 6, rem = t & 63;
        const int bx = rem & 15, by = rem >> 4;
        gemm_body<0, 1, 0, 1, 1>(smA, smB,
            WvfT, APF_D,
            (const void*)(x + (long)zz * APF_T * APF_D), APF_D,
            bvf, (void*)(vTb + (long)zz * 1048576L), APF_T, APF_D,
            (long)by * 128, (long)bx * 128);
    } else {
        const int t = bid - 768;          // 512 blocks: 128 m-tiles x 4 n-tiles
        const int bx = t & 3, by = t >> 2;
        gemm_body<1, 0, 3, 0, 0>(smA, smB,
            (const void*)pred, APF_D,
            WfT, 1024,
            bfu, (void*)Cpre, APF_D, APF_D,
            (long)by * 128, (long)bx * 128);
    }
}

// ---------------- fused attention (R16 body + final-output epilogue) ------
// Grid 512 blocks. bid&7 = batch z (XCD L2); (bid>>3)&31 = Q-tile (64 rows);
// bid>>8 = d-chunk (256 cols). 4 waves (qb=w>>1, sb=w&1), s-block 64, 32 it.
// Per iter (ONE __syncthreads, race-free: syncthreads drains each wave's
// vmcnt+lgkmcnt before the barrier, so after it ALL waves' DMA landed):
//   A: QK on sK[cur] (8 MFMA, Q from regs); issue K(kt+1) DMA -> sK[cur^1];
//      V'(kt) global->reg (8 frags, blocked layout).
//   B: exp + rowsum + sP[cur].  [__syncthreads]
//   C: PV on sP[cur] (16 MFMA) -> oacc accumulates P@V'.
// Epilogue: out = sigmoid(Cpre + oacc*inv) fp32 DIRECT (fusion GEMM folded
// into V' by associativity; rows of P/rs sum to 1 so bvf folds exactly).
// LDS 49.8KB -> 2 blocks/CU. launch_bounds(256,2): no spill.
__global__ __launch_bounds__(256, 2) void attn_fused(
    const u16* __restrict__ qg, const u16* __restrict__ kg,
    const u16* __restrict__ vTg, const float* __restrict__ Cpre,
    float* __restrict__ outg)
{
    __shared__ u16 sK[2][64 * 128];  // 2 x 16 KB
    __shared__ u16 sP[2][64 * 64];   // 2 x 8 KB
    __shared__ float sRS[192];       // partials [4w][32] + inv [64]

    const int tid  = threadIdx.x;
    const int lane = tid & 63;
    const int w    = tid >> 6;       // 0..3
    const int l31  = lane & 31;
    const int hi   = lane >> 5;      // 0..1
    const int qb   = w >> 1;         // QK q-block
    const int sb   = w & 1;          // QK s-block

    const int  bid = blockIdx.x;
    const long z   = bid & 7;
    const int  r   = bid >> 3;
    const long q0  = (long)(r & 31) * 64;
    const long d0  = (long)(r >> 5) * 256;

    const u16* kbase0 = kg + z * (long)APF_T * APF_H;

    // prologue: K tile 0 DMA (pre-swizzled source, linear LDS)
#pragma unroll
    for (int rep = 0; rep < 4; ++rep) {
        const int c    = tid + rep * 256;     // 0..1023
        const int row  = c >> 4;
        const int col8 = (c & 15) * 8;
        load16_lds(kbase0 + row * APF_H + (col8 ^ ((row & 15) << 3)),
                   &sK[0][c * 8]);
    }

    // Q hoist: loop-invariant fragments (lane's q-row = q0 + qb*32 + l31)
    short8 qf[8];
    {
        const u16* qsrc = qg + (z * APF_T + q0 + qb * 32 + l31) * APF_H;
#pragma unroll
        for (int ks = 0; ks < 8; ++ks)
            qf[ks] = *(const short8*)(qsrc + ks * 16 + hi * 8);
    }
    __syncthreads();   // full drain once: sK[0] + qf ready

    f32x16 oacc[2][2];
#pragma unroll
    for (int i = 0; i < 2; ++i)
#pragma unroll
        for (int j = 0; j < 2; ++j) oacc[i][j] = zero16();
    f32x16 rsacc = zero16();

    // blocked v'T base for this wave: [z][dblk][s8][d&31][s&7]
    const long dblk0 = (d0 >> 5) + w * 2;
    const u16* vzb = vTg + z * 1048576L + dblk0 * 65536L + (long)l31 * 8;

    const int krow = sb * 32 + l31;
    const int pcol = sb * 32 + l31;

    int cur = 0;
    for (int kt = 0; kt < APF_T / 64; ++kt) {
        // phase A: QK^T on sK[cur] (Q from regs)
        f32x16 sacc = zero16();
#pragma unroll
        for (int ks = 0; ks < 8; ++ks) {
            const int colk = ks * 16 + hi * 8;
            const short8 bv =
                *(const short8*)&sK[cur][krow * 128 + (colk ^ ((krow & 15) << 3))];
            sacc = __builtin_amdgcn_mfma_f32_32x32x16_bf16(qf[ks], bv, sacc, 0, 0, 0);
        }

        // issue next K tile DMA into the other buffer (drained at the barrier)
        if (kt + 1 < APF_T / 64) {
            const u16* ksrc = kbase0 + (long)(kt + 1) * 64 * APF_H;
#pragma unroll
            for (int rep = 0; rep < 4; ++rep) {
                const int c    = tid + rep * 256;
                const int row  = c >> 4;
                const int col8 = (c & 15) * 8;
                load16_lds(ksrc + row * APF_H + (col8 ^ ((row & 15) << 3)),
                           &sK[cur ^ 1][c * 8]);
            }
        }

        // V' prefetch (blocked layout: contiguous 1KB per instr), 8 frags
        const long sbase = (long)kt * 8 + hi;
        short8 vf[2][4];
#pragma unroll
        for (int dt = 0; dt < 2; ++dt)
#pragma unroll
            for (int ks = 0; ks < 4; ++ks)
                vf[dt][ks] = *(const short8*)(vzb + dt * 65536L + (sbase + ks * 2) * 256);

        // phase B: exp + rowsum + P -> sP[cur] (swizzled)
#pragma unroll
        for (int rg = 0; rg < 16; ++rg) {
            const float e = __expf(sacc[rg]);
            rsacc[rg] += e;
            const int prow = qb * 32 + (rg & 3) + 8 * (rg >> 2) + 4 * hi;
            sP[cur][prow * 64 + (pcol ^ ((prow & 7) << 3))] = f2bf(e);
        }
        __syncthreads();   // sP[cur] visible; all waves' K-DMA + V landed

        // phase C: PV on sP[cur]: O[64][w*64..+64] += P @ V'^T
#pragma unroll
        for (int ks = 0; ks < 4; ++ks) {
            const int colk = ks * 16 + hi * 8;
            short8 pa[2];
#pragma unroll
            for (int qt = 0; qt < 2; ++qt) {
                const int prow = qt * 32 + l31;
                pa[qt] = *(const short8*)&sP[cur][prow * 64 + (colk ^ ((prow & 7) << 3))];
            }
#pragma unroll
            for (int dt = 0; dt < 2; ++dt)
#pragma unroll
                for (int qt = 0; qt < 2; ++qt)
                    oacc[qt][dt] = __builtin_amdgcn_mfma_f32_32x32x16_bf16(
                        pa[qt], vf[dt][ks], oacc[qt][dt], 0, 0, 0);
        }
        cur ^= 1;
    }

    // rowsum: reduce over the 32 s-cols (l31), publish per-wave partials
#pragma unroll
    for (int rg = 0; rg < 16; ++rg) {
        float s = rsacc[rg];
        s += __shfl_xor(s, 1);
        s += __shfl_xor(s, 2);
        s += __shfl_xor(s, 4);
        s += __shfl_xor(s, 8);
        s += __shfl_xor(s, 16);
        rsacc[rg] = s;
    }
    if (l31 == 0) {
#pragma unroll
        for (int rg = 0; rg < 16; ++rg) {
            const int row = (rg & 3) + 8 * (rg >> 2) + 4 * hi;   // 0..31
            sRS[w * 32 + row] = rsacc[rg];
        }
    }
    __syncthreads();
    if (tid < 64) {
        const int qb2 = tid >> 5, r2 = tid & 31;
        sRS[128 + tid] = 1.0f / (sRS[(qb2 * 2 + 0) * 32 + r2] +
                                 sRS[(qb2 * 2 + 1) * 32 + r2]);
    }
    __syncthreads();

    // epilogue: out = sigmoid(Cpre + oacc*inv), fp32, 64 q rows x 64 d cols
    const long rowg0 = z * APF_T + q0;
    const long colg0 = d0 + (long)w * 64;
#pragma unroll
    for (int qt = 0; qt < 2; ++qt)
#pragma unroll
        for (int rg = 0; rg < 16; ++rg) {
            const int row = qt * 32 + (rg & 3) + 8 * (rg >> 2) + 4 * hi;
            const float inv = sRS[128 + row];
#pragma unroll
            for (int dt = 0; dt < 2; ++dt) {
                const long idx = (rowg0 + row) * APF_D + colg0 + dt * 32 + l31;
                const float val = oacc[qt][dt][rg] * inv + Cpre[idx];
                outg[idx] = 1.0f / (1.0f + expf(-val));
            }
        }
}

extern "C" void kernel_launch(void* const* d_in, const int* in_sizes, int n_in,
                              void* d_out, int out_size, void* d_ws, size_t ws_size,
                              hipStream_t stream)
{
    (void)in_sizes; (void)n_in; (void)out_size; (void)ws_size;

    const float* x    = (const float*)d_in[0];
    const float* pred = (const float*)d_in[1];
    const float* Wq   = (const float*)d_in[2];
    const float* bq   = (const float*)d_in[3];
    const float* Wk   = (const float*)d_in[4];
    const float* bk   = (const float*)d_in[5];
    const float* Wv   = (const float*)d_in[6];
    const float* bv   = (const float*)d_in[7];
    const float* Wf   = (const float*)d_in[8];
    const float* bfu  = (const float*)d_in[9];

    // Workspace: Cpre fp32 32MB, bvf, then u16 arrays (~27MB)
    float* Cpre = (float*)d_ws;                        // [16384][512] fp32
    float* bvf  = Cpre + (long)APF_M * APF_D;          // [512] fp32
    u16* wsp  = (u16*)(bvf + APF_D);
    u16* qb   = wsp;                                   // [16384][128]
    u16* kbuf = qb   + (long)APF_M * APF_H;            // [16384][128]
    u16* vTb  = kbuf + (long)APF_M * APF_H;            // [8][16][256][32][8] blocked
    u16* WqT  = vTb  + (long)APF_M * APF_D;            // [128][512]
    u16* WkT  = WqT  + (long)APF_H * APF_D;            // [128][512]
    u16* WfT  = WkT  + (long)APF_H * APF_D;            // [512][1024]
    u16* WvfT = WfT  + (long)APF_D * 2 * APF_D;        // [512][512]

    const dim3 thr(256);

    // weights -> bf16 transposed + bvf (162 blocks)
    prep_w<<<dim3(162), thr, 0, stream>>>(Wq, WqT, Wk, WkT, Wf, WfT, bv, bvf);

    // WvfT = (Wv @ Wf_bot)^T  (16 blocks, tiny)
    wvf_gemm<<<dim3(4, 4), thr, 0, stream>>>(WfT, Wv, WvfT);

    // q,k projections + v'T + Cpre(pred@Wf_top+bf) in one 1280-block launch
    mid_gemms<<<dim3(1280), thr, 0, stream>>>(
        x, pred, WqT, WkT, WvfT, WfT, bq, bk, bvf, bfu, qb, kbuf, vTb, Cpre);

    // fused attention -> final output (fusion GEMM algebraically folded)
    attn_fused<<<dim3(512), thr, 0, stream>>>(qb, kbuf, vTb, Cpre,
                                              (float*)d_out);
}

// Round 12
// 242.562 us; speedup vs baseline: 1.2898x; 1.1383x over previous
//
#include <hip/hip_runtime.h>
#include <hip/hip_bf16.h>

// AttentivePredictionFusion: B=8, T=2048, D=512, H=128. fp32 in, fp32 out.
// R20: revert R19's algebra (fusion_gemm was only ~10us; the serialized
// wvf/bvf prechain cost ~25us). Base = R16 attn (75.7us, race-free single
// __syncthreads) + R17 gemm_body (counted vmcnt, 248.9 total). NEW: mid is
// the dominant non-attn cost (~145us implied; vT re-reads x fp32 x4 = 128MB,
// Cpre re-reads pred fp32 x4 = 128MB, all L2-missing because panel-sharing
// blocks land on different XCDs). Fix = XCD-colocation swizzles (T1):
//  - vT: zz = t&7 -> all 64 blocks of batch z on XCD z; x[z] (4MB) L2-pinned.
//  - Cpre: by = (t&7) + 8*(j>>2), bx = j&3 -> the 4 blocks sharing a pred
//    panel colocate; each XCD holds a 4MB pred slice, 3/4 reads hit L2.
// (768%8==0 and 256%8==0 so t&7 == hardware XCD.)

#define APF_B 8
#define APF_T 2048
#define APF_D 512
#define APF_H 128
#define APF_M (APF_B * APF_T)   // 16384

// gemm LDS slot swizzle (u16 units within a 32-u16 row)
#define GSWZ(row) ((((row) >> 1) & 3) << 3)

typedef unsigned short u16;
typedef __attribute__((ext_vector_type(8))) short short8;
typedef __attribute__((ext_vector_type(4))) float f32x4;
typedef __attribute__((ext_vector_type(16))) float f32x16;

static __device__ __forceinline__ u16 f2bf(float x) {
    union { float f; unsigned int u; } cv;
    cv.f = x;
    unsigned int u = cv.u + 0x7FFFu + ((cv.u >> 16) & 1u);  // RNE
    return (u16)(u >> 16);
}
static __device__ __forceinline__ u16 f2bf_hw(float x) {
    union { __hip_bfloat16 h; u16 u; } cv;
    cv.h = __float2bfloat16(x);
    return cv.u;
}

// async global->LDS, 16 B per lane; LDS dest = wave-uniform base + lane*16
static __device__ __forceinline__ void load16_lds(const u16* g, u16* l) {
    __builtin_amdgcn_global_load_lds(
        (const __attribute__((address_space(1))) unsigned int*)g,
        (__attribute__((address_space(3))) unsigned int*)l,
        16, 0, 0);
}

// barrier that keeps the N newest VMEM ops in flight (T4 counted vmcnt)
template <int N>
static __device__ __forceinline__ void bar_keep() {
    if constexpr (N == 0)
        asm volatile("s_waitcnt vmcnt(0) lgkmcnt(0)\ns_barrier" ::: "memory");
    else if constexpr (N == 4)
        asm volatile("s_waitcnt vmcnt(4) lgkmcnt(0)\ns_barrier" ::: "memory");
    else if constexpr (N == 8)
        asm volatile("s_waitcnt vmcnt(8) lgkmcnt(0)\ns_barrier" ::: "memory");
}

static __device__ __forceinline__ f32x16 zero16() {
    f32x16 v;
#pragma unroll
    for (int i = 0; i < 16; ++i) v[i] = 0.f;
    return v;
}

// ---------------- prep kernel: LDS-tiled weight transposes ----------------
__global__ __launch_bounds__(256) void prep_w(
    const float* __restrict__ Wq, u16* __restrict__ WqT,
    const float* __restrict__ Wk, u16* __restrict__ WkT,
    const float* __restrict__ Wv, u16* __restrict__ WvT,
    const float* __restrict__ Wf, u16* __restrict__ WfT)
{
    __shared__ float tile[64][65];
    int b = blockIdx.x;
    const float* src; u16* dst; int K, N;
    if (b < 16)      { src = Wq; dst = WqT; K = 512;  N = 128; }
    else if (b < 32) { b -= 16; src = Wk; dst = WkT; K = 512;  N = 128; }
    else if (b < 96) { b -= 32; src = Wv; dst = WvT; K = 512;  N = 512; }
    else             { b -= 96; src = Wf; dst = WfT; K = 1024; N = 512; }
    const int ntN = N >> 6;
    const int k0 = (b / ntN) * 64, n0 = (b % ntN) * 64;

    const int tid = threadIdx.x;
#pragma unroll
    for (int rep = 0; rep < 4; ++rep) {
        const int r = (tid >> 4) + rep * 16;     // 0..63 (k)
        const int c = (tid & 15) * 4;            // 0..60 (n)
        const float4 v = *(const float4*)&src[(long)(k0 + r) * N + n0 + c];
        tile[r][c] = v.x; tile[r][c + 1] = v.y;
        tile[r][c + 2] = v.z; tile[r][c + 3] = v.w;
    }
    __syncthreads();
#pragma unroll
    for (int rep = 0; rep < 2; ++rep) {
        const int rn = (tid >> 3) + rep * 32;    // 0..63 (n)
        const int ck = (tid & 7) * 8;            // 0..56 (k)
        short8 o;
#pragma unroll
        for (int j = 0; j < 8; ++j)
            o[j] = (short)f2bf_hw(tile[ck + j][rn]);
        *(short8*)&dst[(long)(n0 + rn) * K + k0 + ck] = o;
    }
}

// ---------------- GEMM body (device function) ----------------
// C[128][128] tile = A[M][K] @ B[N][K]^T (+ bias / + Cadd).
// ADT: 0 = A bf16 (DMA, swizzled src), 1 = A fp32 (reg-stage + HW cvt).
// EPI: 0 bf16 store +bias; 3 fp32 raw +bias; 4 fp32 sigmoid(acc + Cadd).
// BIASM: 0 bias[n]; 1 bias[m].   VBLK: 1 -> blocked [m/32][n/8][m&31][n&7].
// Pipeline per iter: issue regload(t+1) -> bar_keep<NREG> (drains only
// dma(t); regloads cross) -> issue dma(t+1) -> MFMA(t) -> ds_write(t+1).
template <int ADT, int BDT, int EPI, int BIASM, int VBLK>
static __device__ __forceinline__ void gemm_body(
    u16 (&smA)[2][4096], u16 (&smB)[2][4096],
    const void* Ap, long lda,
    const void* Bp, long ldb,
    const float* bias, void* Cp, long ldc, int K,
    long row0, long col0, const float* Cadd)
{
    const int tid  = threadIdx.x;
    const int lane = tid & 63;
    const int wid  = tid >> 6;
    const int wr   = wid >> 1;
    const int wc   = wid & 1;

    f32x4 acc[4][4];
#pragma unroll
    for (int i = 0; i < 4; ++i)
#pragma unroll
        for (int j = 0; j < 4; ++j)
            acc[i][j] = (f32x4){0.f, 0.f, 0.f, 0.f};

    const int lrow = (lane >> 4) * 4;
    const int lcol = lane & 15;
    const int q8   = (lane >> 4) * 8;

    float4 ra[2][2], rb[2][2];

    auto loadA = [&](int kb) {
        if (ADT == 1) {
            const float* Af = (const float*)Ap;
#pragma unroll
            for (int rep = 0; rep < 2; ++rep) {
                const int c = tid + rep * 256;
                const int rr = c >> 2, kc = (c & 3) * 8;
                const float* ga = Af + (row0 + rr) * lda + kb + kc;
                ra[rep][0] = *(const float4*)ga;
                ra[rep][1] = *(const float4*)(ga + 4);
            }
        }
    };
    auto loadB = [&](int kb) {
        if (BDT == 1) {
            const float* Bf = (const float*)Bp;
#pragma unroll
            for (int rep = 0; rep < 2; ++rep) {
                const int c = tid + rep * 256;
                const int rr = c >> 2, kc = (c & 3) * 8;
                const float* gb = Bf + (col0 + rr) * ldb + kb + kc;
                rb[rep][0] = *(const float4*)gb;
                rb[rep][1] = *(const float4*)(gb + 4);
            }
        }
    };
    auto dmaA = [&](int buf, int kb) {
        if (ADT == 0) {
            const u16* Ab = (const u16*)Ap;
#pragma unroll
            for (int rep = 0; rep < 2; ++rep) {
                const int c = tid + rep * 256;
                const int rr = c >> 2, kc = (c & 3) * 8;
                const int wbase = (wid * 64 + rep * 256) * 8;
                load16_lds(Ab + (row0 + rr) * lda + kb + (kc ^ GSWZ(rr)),
                           &smA[buf][wbase]);
            }
        }
    };
    auto dmaB = [&](int buf, int kb) {
        if (BDT == 0) {
            const u16* Bb = (const u16*)Bp;
#pragma unroll
            for (int rep = 0; rep < 2; ++rep) {
                const int c = tid + rep * 256;
                const int rr = c >> 2, kc = (c & 3) * 8;
                const int wbase = (wid * 64 + rep * 256) * 8;
                load16_lds(Bb + (col0 + rr) * ldb + kb + (kc ^ GSWZ(rr)),
                           &smB[buf][wbase]);
            }
        }
    };
    auto cvt8 = [&](const float4& a, const float4& b) {
        short8 v;
        v[0] = (short)f2bf_hw(a.x); v[1] = (short)f2bf_hw(a.y);
        v[2] = (short)f2bf_hw(a.z); v[3] = (short)f2bf_hw(a.w);
        v[4] = (short)f2bf_hw(b.x); v[5] = (short)f2bf_hw(b.y);
        v[6] = (short)f2bf_hw(b.z); v[7] = (short)f2bf_hw(b.w);
        return v;
    };
    auto writeA = [&](int buf) {
        if (ADT == 1) {
#pragma unroll
            for (int rep = 0; rep < 2; ++rep) {
                const int c = tid + rep * 256;
                *(short8*)&smA[buf][(c * 8) ^ GSWZ(c >> 2)] =
                    cvt8(ra[rep][0], ra[rep][1]);
            }
        }
    };
    auto writeB = [&](int buf) {
        if (BDT == 1) {
#pragma unroll
            for (int rep = 0; rep < 2; ++rep) {
                const int c = tid + rep * 256;
                *(short8*)&smB[buf][(c * 8) ^ GSWZ(c >> 2)] =
                    cvt8(rb[rep][0], rb[rep][1]);
            }
        }
    };

    // per-wave VMEM instrs that stay in flight across the barrier
    constexpr int NREG = (ADT == 1 ? 4 : 0) + (BDT == 1 ? 4 : 0);

    const int NT = K / 32;
    loadA(0); loadB(0);
    writeA(0); writeB(0);
    dmaA(0, 0); dmaB(0, 0);

    int cur = 0;
    for (int t = 0; t < NT; ++t) {
        const int kb2 = (t + 1) * 32;
        if (t + 1 < NT) {
            loadA(kb2); loadB(kb2);     // fp32 reg loads: cross the barrier
            bar_keep<NREG>();           // drains dma(t) + prev ds_writes only
            dmaA(cur ^ 1, kb2); dmaB(cur ^ 1, kb2);  // post-bar: WAR-safe
        } else {
            bar_keep<0>();
        }

        short8 av[4], bv4[4];
#pragma unroll
        for (int ti = 0; ti < 4; ++ti) {
            const int arow = wr * 64 + ti * 16 + lcol;
            av[ti] = *(const short8*)&smA[cur][arow * 32 + (q8 ^ GSWZ(arow))];
        }
#pragma unroll
        for (int tj = 0; tj < 4; ++tj) {
            const int brow = wc * 64 + tj * 16 + lcol;
            bv4[tj] = *(const short8*)&smB[cur][brow * 32 + (q8 ^ GSWZ(brow))];
        }

#pragma unroll
        for (int ti = 0; ti < 4; ++ti)
#pragma unroll
            for (int tj = 0; tj < 4; ++tj)
                acc[ti][tj] = __builtin_amdgcn_mfma_f32_16x16x32_bf16(
                    av[ti], bv4[tj], acc[ti][tj], 0, 0, 0);

        if (t + 1 < NT) { writeA(cur ^ 1); writeB(cur ^ 1); }
        cur ^= 1;
    }

#pragma unroll
    for (int ti = 0; ti < 4; ++ti) {
        const long m0t = row0 + wr * 64 + ti * 16 + lrow;
#pragma unroll
        for (int tj = 0; tj < 4; ++tj) {
            const long n = col0 + wc * 64 + tj * 16 + lcol;
            const float bn = (BIASM == 0 && bias != nullptr) ? bias[n] : 0.f;
            if (EPI == 0) {
                u16* C = (u16*)Cp;
#pragma unroll
                for (int r = 0; r < 4; ++r) {
                    const long m = m0t + r;
                    const float bm = (BIASM == 1) ? bias[m] : bn;
                    long idx;
                    if (VBLK) {
                        idx = ((((m >> 5) * 256) + (n >> 3)) << 8) +
                              ((m & 31) << 3) + (n & 7);
                    } else {
                        idx = m * ldc + n;
                    }
                    C[idx] = f2bf_hw(acc[ti][tj][r] + bm);
                }
            } else if (EPI == 3) {
                float* C = (float*)Cp;
#pragma unroll
                for (int r = 0; r < 4; ++r)
                    C[(m0t + r) * ldc + n] = acc[ti][tj][r] + bn;
            } else {  // EPI == 4
                float* C = (float*)Cp;
#pragma unroll
                for (int r = 0; r < 4; ++r) {
                    const float val = acc[ti][tj][r] + Cadd[(m0t + r) * ldc + n];
                    C[(m0t + r) * ldc + n] = 1.0f / (1.0f + expf(-val));
                }
            }
        }
    }
}

// ---------------- mid GEMMs: q/k proj + vT + Cpre, one 1280-block launch ---
// bid<256: qk. zz=bid>>7 (0:q pred/WqT, 1:k x/WkT), by=bid&127 (no reuse).
// 256..767: vT. XCD-swizzle: zz = t&7 (all 64 blocks of batch z colocate on
//   XCD z; x[z] 4MB fp32 = one L2). idx=t>>3: bx=idx&15, by=idx>>4.
// 768..1279: Cpre. XCD-swizzle: the 4 bx-blocks sharing a pred panel get the
//   same t%8: xcd=t&7, j=t>>3, by = xcd + 8*(j>>2), bx = j&3. Each XCD holds
//   a 4MB pred slice; 3/4 panel reads are L2 hits.
__global__ __launch_bounds__(256, 3) void mid_gemms(
    const float* __restrict__ x, const float* __restrict__ pred,
    const u16* __restrict__ WqT, const u16* __restrict__ WkT,
    const u16* __restrict__ WvT, const u16* __restrict__ WfT,
    const float* __restrict__ bq, const float* __restrict__ bk,
    const float* __restrict__ bv, const float* __restrict__ bfu,
    u16* __restrict__ qb, u16* __restrict__ kbuf, u16* __restrict__ vTb,
    float* __restrict__ Cpre)
{
    __shared__ u16 smA[2][4096];
    __shared__ u16 smB[2][4096];

    const int bid = blockIdx.x;
    if (bid < 256) {
        const int zz = bid >> 7, by = bid & 127;
        gemm_body<1, 0, 0, 0, 0>(smA, smB,
            zz ? (const void*)x : (const void*)pred, APF_D,
            zz ? WkT : WqT, APF_D,
            zz ? bk : bq, zz ? (void*)kbuf : (void*)qb, APF_H, APF_D,
            (long)by * 128, 0, nullptr);
    } else if (bid < 768) {
        const int t = bid - 256;          // t%8 == XCD (256%8==0)
        const int zz = t & 7;             // batch z pinned to XCD z
        const int idx = t >> 3;           // 0..63
        const int bx = idx & 15, by = idx >> 4;
        gemm_body<0, 1, 0, 1, 1>(smA, smB,
            WvT, APF_D,
            (const void*)(x + (long)zz * APF_T * APF_D), APF_D,
            bv, (void*)(vTb + (long)zz * 1048576L), APF_T, APF_D,
            (long)by * 128, (long)bx * 128, nullptr);
    } else {
        const int t = bid - 768;          // t%8 == XCD (768%8==0)
        const int xcd = t & 7, j = t >> 3;        // j 0..63
        const int by = xcd + 8 * (j >> 2);        // pred panels colocate
        const int bx = j & 3;
        gemm_body<1, 0, 3, 0, 0>(smA, smB,
            (const void*)pred, APF_D,
            WfT, 1024,
            bfu, (void*)Cpre, APF_D, APF_D,
            (long)by * 128, (long)bx * 128, nullptr);
    }
}

// ---------------- fusion GEMM: out = sigmoid(att@Wf_bot + Cpre) ----------
__global__ __launch_bounds__(256, 2) void fusion_gemm(
    const u16* __restrict__ attb, const u16* __restrict__ WfT,
    const float* __restrict__ Cpre, float* __restrict__ out)
{
    __shared__ u16 smA[2][4096];
    __shared__ u16 smB[2][4096];
    gemm_body<0, 0, 4, 0, 0>(smA, smB,
        (const void*)attb, APF_D,
        WfT + 512, 1024,
        nullptr, (void*)out, APF_D, APF_D,
        (long)blockIdx.y * 128, (long)blockIdx.x * 128, Cpre);
}

// ---------------- fused attention (R16 verbatim: best measured, 75.7us) ---
// Grid 512 blocks. bid&7 = batch z (XCD L2); (bid>>3)&31 = Q-tile (64 rows);
// bid>>8 = d-chunk (256 cols). 4 waves (qb=w>>1, sb=w&1), s-block 64, 32 it.
// Per iter (ONE __syncthreads — drains each wave's vmcnt+lgkmcnt, so after
// it ALL waves' DMA landed; race-free):
//   A: QK on sK[cur] (8 MFMA, Q from regs); issue K(kt+1) DMA -> sK[cur^1];
//      V(kt) global->reg (8 frags, blocked layout).
//   B: exp + rowsum + sP[cur].  [__syncthreads]
//   C: PV on sP[cur] (16 MFMA).
// LDS 49.8KB -> 2 blocks/CU. launch_bounds(256,2): no spill.
__global__ __launch_bounds__(256, 2) void attn_fused(
    const u16* __restrict__ qg, const u16* __restrict__ kg,
    const u16* __restrict__ vTg, u16* __restrict__ attg)
{
    __shared__ u16 sK[2][64 * 128];  // 2 x 16 KB
    __shared__ u16 sP[2][64 * 64];   // 2 x 8 KB
    __shared__ float sRS[192];       // partials [4w][32] + inv [64]

    const int tid  = threadIdx.x;
    const int lane = tid & 63;
    const int w    = tid >> 6;       // 0..3
    const int l31  = lane & 31;
    const int hi   = lane >> 5;      // 0..1
    const int qb   = w >> 1;         // QK q-block
    const int sb   = w & 1;          // QK s-block

    const int  bid = blockIdx.x;
    const long z   = bid & 7;
    const int  r   = bid >> 3;
    const long q0  = (long)(r & 31) * 64;
    const long d0  = (long)(r >> 5) * 256;

    const u16* kbase0 = kg + z * (long)APF_T * APF_H;

    // prologue: K tile 0 DMA (pre-swizzled source, linear LDS)
#pragma unroll
    for (int rep = 0; rep < 4; ++rep) {
        const int c    = tid + rep * 256;     // 0..1023
        const int row  = c >> 4;
        const int col8 = (c & 15) * 8;
        load16_lds(kbase0 + row * APF_H + (col8 ^ ((row & 15) << 3)),
                   &sK[0][c * 8]);
    }

    // Q hoist: loop-invariant fragments (lane's q-row = q0 + qb*32 + l31)
    short8 qf[8];
    {
        const u16* qsrc = qg + (z * APF_T + q0 + qb * 32 + l31) * APF_H;
#pragma unroll
        for (int ks = 0; ks < 8; ++ks)
            qf[ks] = *(const short8*)(qsrc + ks * 16 + hi * 8);
    }
    __syncthreads();   // full drain once: sK[0] + qf ready

    f32x16 oacc[2][2];
#pragma unroll
    for (int i = 0; i < 2; ++i)
#pragma unroll
        for (int j = 0; j < 2; ++j) oacc[i][j] = zero16();
    f32x16 rsacc = zero16();

    // blocked vT base for this wave: [z][dblk][s8][d&31][s&7]
    const long dblk0 = (d0 >> 5) + w * 2;
    const u16* vzb = vTg + z * 1048576L + dblk0 * 65536L + (long)l31 * 8;

    const int krow = sb * 32 + l31;
    const int pcol = sb * 32 + l31;

    int cur = 0;
    for (int kt = 0; kt < APF_T / 64; ++kt) {
        // phase A: QK^T on sK[cur] (Q from regs)
        f32x16 sacc = zero16();
#pragma unroll
        for (int ks = 0; ks < 8; ++ks) {
            const int colk = ks * 16 + hi * 8;
            const short8 bv =
                *(const short8*)&sK[cur][krow * 128 + (colk ^ ((krow & 15) << 3))];
            sacc = __builtin_amdgcn_mfma_f32_32x32x16_bf16(qf[ks], bv, sacc, 0, 0, 0);
        }

        // issue next K tile DMA into the other buffer (drains at the barrier)
        if (kt + 1 < APF_T / 64) {
            const u16* ksrc = kbase0 + (long)(kt + 1) * 64 * APF_H;
#pragma unroll
            for (int rep = 0; rep < 4; ++rep) {
                const int c    = tid + rep * 256;
                const int row  = c >> 4;
                const int col8 = (c & 15) * 8;
                load16_lds(ksrc + row * APF_H + (col8 ^ ((row & 15) << 3)),
                           &sK[cur ^ 1][c * 8]);
            }
        }

        // V prefetch (blocked layout: contiguous 1KB per instr), 8 frags
        const long sbase = (long)kt * 8 + hi;
        short8 vf[2][4];
#pragma unroll
        for (int dt = 0; dt < 2; ++dt)
#pragma unroll
            for (int ks = 0; ks < 4; ++ks)
                vf[dt][ks] = *(const short8*)(vzb + dt * 65536L + (sbase + ks * 2) * 256);

        // phase B: exp + rowsum + P -> sP[cur] (swizzled)
#pragma unroll
        for (int rg = 0; rg < 16; ++rg) {
            const float e = __expf(sacc[rg]);
            rsacc[rg] += e;
            const int prow = qb * 32 + (rg & 3) + 8 * (rg >> 2) + 4 * hi;
            sP[cur][prow * 64 + (pcol ^ ((prow & 7) << 3))] = f2bf(e);
        }
        __syncthreads();   // sP[cur] visible; all waves' K-DMA + V landed

        // phase C: PV on sP[cur]: O[64][w*64..+64] += P @ V^T
#pragma unroll
        for (int ks = 0; ks < 4; ++ks) {
            const int colk = ks * 16 + hi * 8;
            short8 pa[2];
#pragma unroll
            for (int qt = 0; qt < 2; ++qt) {
                const int prow = qt * 32 + l31;
                pa[qt] = *(const short8*)&sP[cur][prow * 64 + (colk ^ ((prow & 7) << 3))];
            }
#pragma unroll
            for (int dt = 0; dt < 2; ++dt)
#pragma unroll
                for (int qt = 0; qt < 2; ++qt)
                    oacc[qt][dt] = __builtin_amdgcn_mfma_f32_32x32x16_bf16(
                        pa[qt], vf[dt][ks], oacc[qt][dt], 0, 0, 0);
        }
        cur ^= 1;
    }

    // rowsum: reduce over the 32 s-cols (l31), publish per-wave partials
#pragma unroll
    for (int rg = 0; rg < 16; ++rg) {
        float s = rsacc[rg];
        s += __shfl_xor(s, 1);
        s += __shfl_xor(s, 2);
        s += __shfl_xor(s, 4);
        s += __shfl_xor(s, 8);
        s += __shfl_xor(s, 16);
        rsacc[rg] = s;
    }
    if (l31 == 0) {
#pragma unroll
        for (int rg = 0; rg < 16; ++rg) {
            const int row = (rg & 3) + 8 * (rg >> 2) + 4 * hi;   // 0..31
            sRS[w * 32 + row] = rsacc[rg];
        }
    }
    __syncthreads();
    if (tid < 64) {
        const int qb2 = tid >> 5, r2 = tid & 31;
        sRS[128 + tid] = 1.0f / (sRS[(qb2 * 2 + 0) * 32 + r2] +
                                 sRS[(qb2 * 2 + 1) * 32 + r2]);
    }
    __syncthreads();

    // store: 64 q rows x own 64 d cols
    const long rowg0 = z * APF_T + q0;
    const long colg0 = d0 + (long)w * 64;
#pragma unroll
    for (int qt = 0; qt < 2; ++qt)
#pragma unroll
        for (int rg = 0; rg < 16; ++rg) {
            const int row = qt * 32 + (rg & 3) + 8 * (rg >> 2) + 4 * hi;
            const float inv = sRS[128 + row];
#pragma unroll
            for (int dt = 0; dt < 2; ++dt)
                attg[(rowg0 + row) * APF_D + colg0 + dt * 32 + l31] =
                    f2bf(oacc[qt][dt][rg] * inv);
        }
}

extern "C" void kernel_launch(void* const* d_in, const int* in_sizes, int n_in,
                              void* d_out, int out_size, void* d_ws, size_t ws_size,
                              hipStream_t stream)
{
    (void)in_sizes; (void)n_in; (void)out_size; (void)ws_size;

    const float* x    = (const float*)d_in[0];
    const float* pred = (const float*)d_in[1];
    const float* Wq   = (const float*)d_in[2];
    const float* bq   = (const float*)d_in[3];
    const float* Wk   = (const float*)d_in[4];
    const float* bk   = (const float*)d_in[5];
    const float* Wv   = (const float*)d_in[6];
    const float* bv   = (const float*)d_in[7];
    const float* Wf   = (const float*)d_in[8];
    const float* bfu  = (const float*)d_in[9];

    // Workspace: Cpre fp32 32MB first, then u16 arrays (~42MB)
    float* Cpre = (float*)d_ws;                        // [16384][512] fp32
    u16* wsp  = (u16*)(Cpre + (long)APF_M * APF_D);
    u16* qb   = wsp;                                   // [16384][128]
    u16* kbuf = qb   + (long)APF_M * APF_H;            // [16384][128]
    u16* vTb  = kbuf + (long)APF_M * APF_H;            // [8][16][256][32][8] blocked
    u16* attb = vTb  + (long)APF_M * APF_D;            // [16384][512]
    u16* WqT  = attb + (long)APF_M * APF_D;            // [128][512]
    u16* WkT  = WqT  + (long)APF_H * APF_D;            // [128][512]
    u16* WvT  = WkT  + (long)APF_H * APF_D;            // [512][512]
    u16* WfT  = WvT  + (long)APF_D * APF_D;            // [512][1024]

    const dim3 thr(256);

    // weights -> bf16 transposed (LDS-tiled, coalesced)
    prep_w<<<dim3(224), thr, 0, stream>>>(Wq, WqT, Wk, WkT, Wv, WvT, Wf, WfT);

    // q,k projections + vT + Cpre(pred@Wf_top+bf) in one 1280-block launch
    mid_gemms<<<dim3(1280), thr, 0, stream>>>(
        x, pred, WqT, WkT, WvT, WfT, bq, bk, bv, bfu, qb, kbuf, vTb, Cpre);

    // fused attention: att = softmax(q k^T) v
    attn_fused<<<dim3(512), thr, 0, stream>>>(qb, kbuf, vTb, attb);

    // out = sigmoid(att @ Wf_bot + Cpre)
    fusion_gemm<<<dim3(4, 128), thr, 0, stream>>>(attb, WfT, Cpre,
                                                  (float*)d_out);
}